// Round 7
// baseline (561.422 us; speedup 1.0000x reference)
//
#include <hip/hip_runtime.h>
#include <math.h>

// ---------------------------------------------------------------------------
// GAT IoT classifier — round 28: XCD-sliced aggregate, 8 nodes/wave.
// r27 post-mortem: head fusion = serial 256-step readlane chain -> 250 us,
// reverted. r22 evidence: XCD slicing cuts FETCH 208.8->76 MB (L2-locality
// works) but 1 node/wave duplicated setup+logit VALU (76% busy, 172 us).
// r28: slice kernel with 8 nodes/wave; lane = slot(16 edges) x colg(4x8 cols)
// -> inner loop has ZERO shuffles (per-slot logit, colg dup is lane-parallel),
// h-gathers are 16 rows x 64B per inst, L2-resident (3.2MB slice < 4MB L2).
// GEMMs/head: r21 64-tile (measured best) + r22-proven blocked [8][Mp][32]
// C-write/A-read. Predicted: agg ~30-42 us, FETCH 60-90MB, total ~300-320.
// ---------------------------------------------------------------------------

typedef __attribute__((ext_vector_type(8))) _Float16 half8v;  // 8 fp16 (4 VGPRs)
typedef __attribute__((ext_vector_type(4))) float f32x4;

__device__ __forceinline__ float lrelu(float x) { return x > 0.f ? x : 0.2f * x; }
__device__ __forceinline__ float elu1(float x) { return x > 0.f ? x : (__expf(x) - 1.f); }

// ---------------- weights -> transposed fp16 + indeg zeroing, one launch ------
__global__ void convert_weights_kernel(const float* __restrict__ W1, const float* __restrict__ W2,
                                       const float* __restrict__ lw1,
                                       _Float16* __restrict__ o1, _Float16* __restrict__ o2,
                                       _Float16* __restrict__ o3, int* __restrict__ indeg,
                                       int N) {
  int t = blockIdx.x * blockDim.x + threadIdx.x;
  if (t < 32768) {                       // W1
    int n = t >> 7, k = t & 127;
    o1[t] = (_Float16)W1[(long)k * 256 + n];
  } else if (t < 98304) {                // W2
    int i = t - 32768;
    int n = i >> 8, k = i & 255;
    o2[i] = (_Float16)W2[(long)k * 256 + n];
  } else if (t < 114688) {               // lw1
    int i = t - 98304;
    int n = i >> 8, k = i & 255;
    o3[i] = (_Float16)lw1[(long)k * 64 + n];
  } else if (t < 114688 + N) {           // indeg zeroing
    indeg[t - 114688] = 0;
  }
}

// ---------------- CSR build ----------------
__global__ void count_kernel(const int* __restrict__ dst, int E, int* __restrict__ indeg) {
  int e = blockIdx.x * blockDim.x + threadIdx.x;
  if (e < E) atomicAdd(&indeg[dst[e]], 1);
}

__global__ void scan_block_kernel(const int* __restrict__ in, int* __restrict__ incl,
                                  int* __restrict__ bsum, int N) {
  __shared__ int wsum[16];
  int gid = blockIdx.x * 1024 + threadIdx.x;
  int lane = threadIdx.x & 63, w = threadIdx.x >> 6;
  int v = (gid < N) ? in[gid] : 0;
  int sv = v;
#pragma unroll
  for (int o = 1; o < 64; o <<= 1) {
    int t = __shfl_up(sv, o);
    if (lane >= o) sv += t;
  }
  if (lane == 63) wsum[w] = sv;
  __syncthreads();
  if (w == 0) {
    int bs = (lane < 16) ? wsum[lane] : 0;
#pragma unroll
    for (int o = 1; o < 16; o <<= 1) {
      int t = __shfl_up(bs, o);
      if (lane >= o) bs += t;
    }
    if (lane < 16) wsum[lane] = bs;
  }
  __syncthreads();
  if (w > 0) sv += wsum[w - 1];
  if (gid < N) incl[gid] = sv;
  if (threadIdx.x == 1023) bsum[blockIdx.x] = sv;
}

__global__ void scan_finalize_kernel(const int* __restrict__ in, const int* __restrict__ incl,
                                     const int* __restrict__ bsum, int* __restrict__ off,
                                     int* __restrict__ cursor, int N) {
  int gid = blockIdx.x * blockDim.x + threadIdx.x;
  if (gid >= N) return;
  int b = gid >> 10;
  int carry = 0;
  for (int k = 0; k < b; ++k) carry += bsum[k];
  int ic = incl[gid] + carry;
  off[gid + 1] = ic;
  cursor[gid] = ic - in[gid];
  if (gid == 0) off[0] = 0;
}

__global__ void fill_kernel(const int* __restrict__ src, const int* __restrict__ dst, int E,
                            int* __restrict__ cursor, int* __restrict__ csr_src) {
  int e = blockIdx.x * blockDim.x + threadIdx.x;
  if (e < E) {
    int pos = atomicAdd(&cursor[dst[e]], 1);
    csr_src[pos] = src[e];
  }
}

// ---------------- fp16 MFMA GEMM (r21 64-tile) + attn epilogue, blocked C --
// C written as [8][Mp][32] (col block = col>>5). A: fp32 row-major (layer 1)
// or fp16 blocked (layer 2).
template <typename AT>
__launch_bounds__(256)
__global__ void mfma_gemm_attn_kernel(const AT* __restrict__ A,
                                      const _Float16* __restrict__ B,
                                      const float* __restrict__ att_s,
                                      const float* __restrict__ att_d,
                                      _Float16* __restrict__ C,
                                      float* __restrict__ a_s, float* __restrict__ a_d,
                                      int M, int K, int Mp) {
  __shared__ _Float16 As[64][40];
  __shared__ _Float16 Bs[2][64][40];
  int tid = threadIdx.x;
  int bm = blockIdx.y * 64, bn = blockIdx.x * 128;
  int lane = tid & 63, wave = tid >> 6;
  int srow = tid >> 2, sch = (tid & 3) * 8;
  const AT* Ap;
  if constexpr (sizeof(AT) == 4) {
    Ap = A + (long)(bm + srow) * K + sch;            // row-major fp32
  } else {
    Ap = A + (long)(bm + srow) * 32 + sch;           // blocked fp16
  }
  const _Float16* Bp0 = B + (long)(bn + srow) * K + sch;
  const _Float16* Bp1 = B + (long)(bn + 64 + srow) * K + sch;
  bool arow_ok = (bm + srow) < M;
  int fm = lane & 15, fq = lane >> 4;
  f32x4 acc[2][4];
#pragma unroll
  for (int t = 0; t < 2; ++t)
#pragma unroll
    for (int cb = 0; cb < 4; ++cb) acc[t][cb] = (f32x4){0.f, 0.f, 0.f, 0.f};
  for (int k0 = 0; k0 < K; k0 += 32) {
    half8v a8 = {0, 0, 0, 0, 0, 0, 0, 0};
    if (arow_ok) {
      if constexpr (sizeof(AT) == 4) {
        float4 f0 = *(const float4*)(Ap + k0);
        float4 f1 = *(const float4*)(Ap + k0 + 4);
        a8 = (half8v){(_Float16)f0.x, (_Float16)f0.y, (_Float16)f0.z, (_Float16)f0.w,
                      (_Float16)f1.x, (_Float16)f1.y, (_Float16)f1.z, (_Float16)f1.w};
      } else {
        a8 = *(const half8v*)(Ap + (long)(k0 >> 5) * Mp * 32);
      }
    }
    uint4 vb0 = *(const uint4*)(Bp0 + k0);
    uint4 vb1 = *(const uint4*)(Bp1 + k0);
    *(half8v*)&As[srow][sch] = a8;
    *(uint4*)&Bs[0][srow][sch] = vb0;
    *(uint4*)&Bs[1][srow][sch] = vb1;
    __syncthreads();
    half8v ah = *(const half8v*)&As[wave * 16 + fm][fq * 8];
#pragma unroll
    for (int t = 0; t < 2; ++t)
#pragma unroll
      for (int cb = 0; cb < 4; ++cb) {
        half8v bh = *(const half8v*)&Bs[t][cb * 16 + fm][fq * 8];
        acc[t][cb] = __builtin_amdgcn_mfma_f32_16x16x32_f16(ah, bh, acc[t][cb], 0, 0, 0);
      }
    __syncthreads();
  }
  int row0 = bm + wave * 16 + fq * 4;
#pragma unroll
  for (int t = 0; t < 2; ++t) {
    int headi = blockIdx.x * 2 + t;
    int cbase = bn + t * 64;
    float asv[4], adv[4];
#pragma unroll
    for (int cb = 0; cb < 4; ++cb) {
      int col = cbase + cb * 16 + fm;
      asv[cb] = att_s[col];
      adv[cb] = att_d[col];
    }
#pragma unroll
    for (int r = 0; r < 4; ++r) {
      int row = row0 + r;
      float sp = 0.f, dp = 0.f;
#pragma unroll
      for (int cb = 0; cb < 4; ++cb) {
        float v = acc[t][cb][r];
        sp = fmaf(v, asv[cb], sp);
        dp = fmaf(v, adv[cb], dp);
        if (row < M) {
          int col = cbase + cb * 16 + fm;
          C[((long)(col >> 5) * Mp + row) * 32 + (col & 31)] = (_Float16)v;
        }
      }
#pragma unroll
      for (int o = 1; o < 16; o <<= 1) {
        sp += __shfl_xor(sp, o);
        dp += __shfl_xor(dp, o);
      }
      if (fm == 0 && row < M) {
        a_s[(long)row * 4 + headi] = sp;
        a_d[(long)row * 4 + headi] = dp;
      }
    }
  }
}

// ---------------- fused fp16 MFMA head (blocked A) ----------------
__launch_bounds__(256)
__global__ void head_mfma_kernel(const _Float16* __restrict__ A, const _Float16* __restrict__ B,
                                 const float* __restrict__ lb1, const float* __restrict__ lw2,
                                 const float* __restrict__ lb2, float* __restrict__ out,
                                 int M, int Mp) {
  __shared__ _Float16 As[64][40];
  __shared__ _Float16 Bs[64][40];
  int tid = threadIdx.x;
  int bm = blockIdx.x * 64;
  int lane = tid & 63, wave = tid >> 6;
  int srow = tid >> 2, sch = (tid & 3) * 8;
  const _Float16* Ap = A + (long)(bm + srow) * 32 + sch;  // blocked [8][Mp][32]
  const _Float16* Bp = B + (long)srow * 256 + sch;
  int fm = lane & 15, fq = lane >> 4;
  f32x4 acc[4];
#pragma unroll
  for (int cb = 0; cb < 4; ++cb) acc[cb] = (f32x4){0.f, 0.f, 0.f, 0.f};
  for (int k0 = 0; k0 < 256; k0 += 32) {
    uint4 va = *(const uint4*)(Ap + (long)(k0 >> 5) * Mp * 32);
    uint4 vb = *(const uint4*)(Bp + k0);
    *(uint4*)&As[srow][sch] = va;
    *(uint4*)&Bs[srow][sch] = vb;
    __syncthreads();
    half8v ah = *(const half8v*)&As[wave * 16 + fm][fq * 8];
#pragma unroll
    for (int cb = 0; cb < 4; ++cb) {
      half8v bh = *(const half8v*)&Bs[cb * 16 + fm][fq * 8];
      acc[cb] = __builtin_amdgcn_mfma_f32_16x16x32_f16(ah, bh, acc[cb], 0, 0, 0);
    }
    __syncthreads();
  }
  float lb1c[4], w20[4], w21[4];
#pragma unroll
  for (int cb = 0; cb < 4; ++cb) {
    int col = cb * 16 + fm;
    lb1c[cb] = lb1[col];
    w20[cb] = lw2[col * 2 + 0];
    w21[cb] = lw2[col * 2 + 1];
  }
  float b20 = lb2[0], b21 = lb2[1];
#pragma unroll
  for (int r = 0; r < 4; ++r) {
    float v0 = 0.f, v1 = 0.f;
#pragma unroll
    for (int cb = 0; cb < 4; ++cb) {
      float s = fmaxf(acc[cb][r] + lb1c[cb], 0.f);
      v0 = fmaf(s, w20[cb], v0);
      v1 = fmaf(s, w21[cb], v1);
    }
#pragma unroll
    for (int o = 1; o < 16; o <<= 1) {
      v0 += __shfl_xor(v0, o);
      v1 += __shfl_xor(v1, o);
    }
    if (fm == 0) {
      int row = bm + wave * 16 + fq * 4 + r;
      if (row < M) {
        v0 += b20;
        v1 += b21;
        float mx = fmaxf(v0, v1);
        float ls = mx + logf(expf(v0 - mx) + expf(v1 - mx));
        out[(long)row * 2 + 0] = v0 - ls;
        out[(long)row * 2 + 1] = v1 - ls;
      }
    }
  }
}

// ---------------- XCD-sliced aggregation, 8 nodes per wave ----------------
// Grid: 8 slices x cdiv(N,32) groups; slice = blockIdx & 7 -> XCD pinning
// (round-robin dispatch). Wave handles 8 consecutive nodes of its slice
// (32 cols, 3.2 MB -> L2-resident). lane = slot(lane>>2, 16 edge slots) x
// colg(lane&3, 8 cols each). No shuffles in the inner loop: each slot-lane
// computes its edge's logit (colg-duplicated across lanes, instruction-free);
// h-gather = one dwordx4 inst covers 16 rows x 64B. Reduce across slots via
// 4 shfl_xor at node end. alpha = exp(lrelu(l)) (no-max, r24-verified).
__launch_bounds__(256)
__global__ void gat_aggregate_slice8_kernel(const _Float16* __restrict__ hblk,
                                            const float* __restrict__ a_s,
                                            const float* __restrict__ a_d,
                                            const int* __restrict__ off,
                                            const int* __restrict__ csr_src,
                                            const float* __restrict__ bias,
                                            _Float16* __restrict__ outblk,
                                            int N, int Mp) {
  int bid = blockIdx.x;
  int slice = bid & 7;
  int wave = threadIdx.x >> 6, lane = threadIdx.x & 63;
  int node0 = (bid >> 3) * 32 + wave * 8;
  int colg = lane & 3, slot = lane >> 2;
  int hb = slice >> 1;  // head of this slice
  const _Float16* hs = hblk + (long)slice * Mp * 32;
  _Float16* os = outblk + (long)slice * Mp * 32;
  float bs[8];
#pragma unroll
  for (int j = 0; j < 8; ++j) bs[j] = bias[slice * 32 + colg * 8 + j];
  for (int n = 0; n < 8; ++n) {
    int wid = node0 + n;
    if (wid >= N) break;
    int beg = off[wid], cnt = off[wid + 1] - beg;
    float ad_self = a_d[(long)wid * 4 + hb];
    float pself = __expf(lrelu(a_s[(long)wid * 4 + hb] + ad_self));
    float z = (slot == 0) ? pself : 0.f;
    float acc[8];
    if (slot == 0) {
      half8v sr = *(const half8v*)(hs + (long)wid * 32 + colg * 8);
#pragma unroll
      for (int j = 0; j < 8; ++j) acc[j] = pself * (float)sr[j];
    } else {
#pragma unroll
      for (int j = 0; j < 8; ++j) acc[j] = 0.f;
    }
    for (int c0 = 0; c0 < cnt; c0 += 16) {
      int i = c0 + slot;
      bool ok = i < cnt;
      int sv = ok ? csr_src[beg + i] : 0;
      float l = lrelu(a_s[(long)sv * 4 + hb] + ad_self);
      float p = ok ? __expf(l) : 0.f;
      z += p;
      half8v rv = *(const half8v*)(hs + (long)sv * 32 + colg * 8);
      acc[0] = fmaf(p, (float)rv[0], acc[0]);
      acc[1] = fmaf(p, (float)rv[1], acc[1]);
      acc[2] = fmaf(p, (float)rv[2], acc[2]);
      acc[3] = fmaf(p, (float)rv[3], acc[3]);
      acc[4] = fmaf(p, (float)rv[4], acc[4]);
      acc[5] = fmaf(p, (float)rv[5], acc[5]);
      acc[6] = fmaf(p, (float)rv[6], acc[6]);
      acc[7] = fmaf(p, (float)rv[7], acc[7]);
    }
    // reduce across 16 slots (lane bits 2..5)
#pragma unroll
    for (int mask = 4; mask <= 32; mask <<= 1) {
      z += __shfl_xor(z, mask);
#pragma unroll
      for (int j = 0; j < 8; ++j) acc[j] += __shfl_xor(acc[j], mask);
    }
    if (slot == 0) {
      float inv = 1.f / z;  // z >= pself > 0
      half8v o;
#pragma unroll
      for (int j = 0; j < 8; ++j) o[j] = (_Float16)elu1(fmaf(acc[j], inv, bs[j]));
      *(half8v*)(os + (long)wid * 32 + colg * 8) = o;
    }
  }
}

// ---------------------------------------------------------------------------
static inline int cdiv(int a, int b) { return (a + b - 1) / b; }

extern "C" void kernel_launch(void* const* d_in, const int* in_sizes, int n_in,
                              void* d_out, int out_size, void* d_ws, size_t ws_size,
                              hipStream_t stream) {
  const float* x = (const float*)d_in[0];
  const int* ei = (const int*)d_in[1];
  const float* W1 = (const float*)d_in[2];
  const float* as1 = (const float*)d_in[3];
  const float* ad1 = (const float*)d_in[4];
  const float* b1 = (const float*)d_in[5];
  const float* W2 = (const float*)d_in[6];
  const float* as2 = (const float*)d_in[7];
  const float* ad2 = (const float*)d_in[8];
  const float* b2 = (const float*)d_in[9];
  const float* lw1 = (const float*)d_in[10];
  const float* lb1 = (const float*)d_in[11];
  const float* lw2 = (const float*)d_in[12];
  const float* lb2 = (const float*)d_in[13];
  float* out = (float*)d_out;

  int N = in_sizes[0] / 128;  // 50000
  int E = in_sizes[1] / 2;    // 800000
  int Mp = cdiv(N, 64) * 64;  // 50048

  char* ws = (char*)d_ws;
  _Float16* Wt1 = (_Float16*)ws; ws += 256 * 128 * 2;
  _Float16* Wt2 = (_Float16*)ws; ws += 256 * 256 * 2;
  _Float16* WL = (_Float16*)ws; ws += 64 * 256 * 2;
  _Float16* C = (_Float16*)ws; ws += (size_t)Mp * 256 * 2;   // GEMM out (blocked)
  _Float16* h2 = (_Float16*)ws; ws += (size_t)Mp * 256 * 2;  // aggregate out (blocked)
  float* aS = (float*)ws; ws += (size_t)N * 4 * 4;
  float* aD = (float*)ws; ws += (size_t)N * 4 * 4;
  int* csr_src = (int*)ws; ws += (size_t)E * 4;
  int* indeg = (int*)ws; ws += (size_t)N * 4;
  int* cursor = (int*)ws; ws += (size_t)N * 4;
  int* off = (int*)ws; ws += (size_t)(N + 4) * 4;
  int* incl = (int*)ws; ws += (size_t)N * 4;
  int* bsum = (int*)ws; ws += 64 * 4;

  const int* e_src = ei;
  const int* e_dst = ei + E;
  int nb = cdiv(N, 1024);

  // weight conversion + indeg zeroing (one launch)
  convert_weights_kernel<<<cdiv(114688 + N, 256), 256, 0, stream>>>(W1, W2, lw1, Wt1, Wt2, WL,
                                                                    indeg, N);

  // CSR build
  count_kernel<<<cdiv(E, 256), 256, 0, stream>>>(e_dst, E, indeg);
  scan_block_kernel<<<nb, 1024, 0, stream>>>(indeg, incl, bsum, N);
  scan_finalize_kernel<<<cdiv(N, 256), 256, 0, stream>>>(indeg, incl, bsum, off, cursor, N);
  fill_kernel<<<cdiv(E, 256), 256, 0, stream>>>(e_src, e_dst, E, cursor, csr_src);

  int agg_blocks = 8 * cdiv(N, 32);

  // Layer 1 (K=128, fp32 A)
  mfma_gemm_attn_kernel<float><<<dim3(2, Mp / 64), 256, 0, stream>>>(x, Wt1, as1, ad1, C, aS, aD,
                                                                     N, 128, Mp);
  gat_aggregate_slice8_kernel<<<agg_blocks, 256, 0, stream>>>(C, aS, aD, off, csr_src, b1, h2, N,
                                                              Mp);

  // Layer 2 (K=256, fp16 blocked A)
  mfma_gemm_attn_kernel<_Float16><<<dim3(2, Mp / 64), 256, 0, stream>>>(h2, Wt2, as2, ad2, C, aS,
                                                                        aD, N, 256, Mp);
  gat_aggregate_slice8_kernel<<<agg_blocks, 256, 0, stream>>>(C, aS, aD, off, csr_src, b2, h2, N,
                                                              Mp);

  // Head (blocked A, fused epilogue)
  head_mfma_kernel<<<Mp / 64, 256, 0, stream>>>(h2, WL, lb1, lw2, lb2, out, N, Mp);
}

// Round 8
// 376.850 us; speedup vs baseline: 1.4898x; 1.4898x over previous
//
#include <hip/hip_runtime.h>
#include <math.h>

// ---------------------------------------------------------------------------
// GAT IoT classifier — round 29: 2-half XCD-pinned aggregate, r21 GEMMs.
// Slice-family ledger: 8 slices cuts FETCH 208->103 MB but x8 per-node
// overhead saturates VALU (74%, 182 us; r22/r28). 1 slice = 66.3 us at the
// 3.6 TB/s random-gather plateau (FETCH 208 MB = 8-XCD full-table sweep).
// Optimum between: 2 halves of 128 cols. Inner loop stays column-parallel
// (+5% VALU); only setup/epilogue duplicate x2 (~+85 insts/node ~ +3.5 us).
// h-traffic: 2 x (4 XCDs x 12.8 MB) ~ 100 MB. Row-major C unchanged: a
// half = its own 4 cache lines per 512B row -> XCD pinned to a half never
// fetches the other half's lines. GEMMs/head/CSR byte-identical r21
// (measured optimum). half = (blockIdx&7)>>2 (XCD = bid%8, r22/r28-verified);
// 1 node/wave; no-max exp (r24/r25-verified, absmax identical).
// Predicted: agg 45-55 us, FETCH 95-130 MB; total ~340-360.
// ---------------------------------------------------------------------------

typedef __attribute__((ext_vector_type(8))) _Float16 half8v;  // 8 fp16 (4 VGPRs)
typedef __attribute__((ext_vector_type(4))) float f32x4;

__device__ __forceinline__ float lrelu(float x) { return x > 0.f ? x : 0.2f * x; }
__device__ __forceinline__ float elu1(float x) { return x > 0.f ? x : (__expf(x) - 1.f); }

// ---------------- weights -> transposed fp16 + indeg zeroing, one launch ------
__global__ void convert_weights_kernel(const float* __restrict__ W1, const float* __restrict__ W2,
                                       const float* __restrict__ lw1,
                                       _Float16* __restrict__ o1, _Float16* __restrict__ o2,
                                       _Float16* __restrict__ o3, int* __restrict__ indeg,
                                       int N) {
  int t = blockIdx.x * blockDim.x + threadIdx.x;
  if (t < 32768) {                       // W1
    int n = t >> 7, k = t & 127;
    o1[t] = (_Float16)W1[(long)k * 256 + n];
  } else if (t < 98304) {                // W2
    int i = t - 32768;
    int n = i >> 8, k = i & 255;
    o2[i] = (_Float16)W2[(long)k * 256 + n];
  } else if (t < 114688) {               // lw1
    int i = t - 98304;
    int n = i >> 8, k = i & 255;
    o3[i] = (_Float16)lw1[(long)k * 64 + n];
  } else if (t < 114688 + N) {           // indeg zeroing
    indeg[t - 114688] = 0;
  }
}

// ---------------- CSR build ----------------
__global__ void count_kernel(const int* __restrict__ dst, int E, int* __restrict__ indeg) {
  int e = blockIdx.x * blockDim.x + threadIdx.x;
  if (e < E) atomicAdd(&indeg[dst[e]], 1);
}

__global__ void scan_block_kernel(const int* __restrict__ in, int* __restrict__ incl,
                                  int* __restrict__ bsum, int N) {
  __shared__ int wsum[16];
  int gid = blockIdx.x * 1024 + threadIdx.x;
  int lane = threadIdx.x & 63, w = threadIdx.x >> 6;
  int v = (gid < N) ? in[gid] : 0;
  int sv = v;
#pragma unroll
  for (int o = 1; o < 64; o <<= 1) {
    int t = __shfl_up(sv, o);
    if (lane >= o) sv += t;
  }
  if (lane == 63) wsum[w] = sv;
  __syncthreads();
  if (w == 0) {
    int bs = (lane < 16) ? wsum[lane] : 0;
#pragma unroll
    for (int o = 1; o < 16; o <<= 1) {
      int t = __shfl_up(bs, o);
      if (lane >= o) bs += t;
    }
    if (lane < 16) wsum[lane] = bs;
  }
  __syncthreads();
  if (w > 0) sv += wsum[w - 1];
  if (gid < N) incl[gid] = sv;
  if (threadIdx.x == 1023) bsum[blockIdx.x] = sv;
}

__global__ void scan_finalize_kernel(const int* __restrict__ in, const int* __restrict__ incl,
                                     const int* __restrict__ bsum, int* __restrict__ off,
                                     int* __restrict__ cursor, int N) {
  int gid = blockIdx.x * blockDim.x + threadIdx.x;
  if (gid >= N) return;
  int b = gid >> 10;
  int carry = 0;
  for (int k = 0; k < b; ++k) carry += bsum[k];
  int ic = incl[gid] + carry;
  off[gid + 1] = ic;
  cursor[gid] = ic - in[gid];
  if (gid == 0) off[0] = 0;
}

__global__ void fill_kernel(const int* __restrict__ src, const int* __restrict__ dst, int E,
                            int* __restrict__ cursor, int* __restrict__ csr_src) {
  int e = blockIdx.x * blockDim.x + threadIdx.x;
  if (e < E) {
    int pos = atomicAdd(&cursor[dst[e]], 1);
    csr_src[pos] = src[e];
  }
}

// ---------------- fp16 MFMA GEMM (r21 64-tile) + attn epilogue -------------
// C[M,256] = A[M,K] x W[K,256]; W transposed [256][K]. Row-major C.
template <typename AT>
__launch_bounds__(256)
__global__ void mfma_gemm_attn_kernel(const AT* __restrict__ A,
                                      const _Float16* __restrict__ B,
                                      const float* __restrict__ att_s,
                                      const float* __restrict__ att_d,
                                      _Float16* __restrict__ C,
                                      float* __restrict__ a_s, float* __restrict__ a_d,
                                      int M, int K) {
  __shared__ _Float16 As[64][40];     // 10.2+5.1 KB total: residency-safe
  __shared__ _Float16 Bs[2][64][40];
  int tid = threadIdx.x;
  int bm = blockIdx.y * 64, bn = blockIdx.x * 128;
  int lane = tid & 63, wave = tid >> 6;
  int srow = tid >> 2, sch = (tid & 3) * 8;
  const AT* Ap = A + (long)(bm + srow) * K + sch;
  const _Float16* Bp0 = B + (long)(bn + srow) * K + sch;
  const _Float16* Bp1 = B + (long)(bn + 64 + srow) * K + sch;
  bool arow_ok = (bm + srow) < M;
  int fm = lane & 15, fq = lane >> 4;
  f32x4 acc[2][4];
#pragma unroll
  for (int t = 0; t < 2; ++t)
#pragma unroll
    for (int cb = 0; cb < 4; ++cb) acc[t][cb] = (f32x4){0.f, 0.f, 0.f, 0.f};
  for (int k0 = 0; k0 < K; k0 += 32) {
    half8v a8 = {0, 0, 0, 0, 0, 0, 0, 0};
    if (arow_ok) {
      if constexpr (sizeof(AT) == 4) {
        float4 f0 = *(const float4*)(Ap + k0);
        float4 f1 = *(const float4*)(Ap + k0 + 4);
        a8 = (half8v){(_Float16)f0.x, (_Float16)f0.y, (_Float16)f0.z, (_Float16)f0.w,
                      (_Float16)f1.x, (_Float16)f1.y, (_Float16)f1.z, (_Float16)f1.w};
      } else {
        a8 = *(const half8v*)(Ap + k0);
      }
    }
    uint4 vb0 = *(const uint4*)(Bp0 + k0);
    uint4 vb1 = *(const uint4*)(Bp1 + k0);
    *(half8v*)&As[srow][sch] = a8;
    *(uint4*)&Bs[0][srow][sch] = vb0;
    *(uint4*)&Bs[1][srow][sch] = vb1;
    __syncthreads();
    half8v ah = *(const half8v*)&As[wave * 16 + fm][fq * 8];
#pragma unroll
    for (int t = 0; t < 2; ++t)
#pragma unroll
      for (int cb = 0; cb < 4; ++cb) {
        half8v bh = *(const half8v*)&Bs[t][cb * 16 + fm][fq * 8];
        acc[t][cb] = __builtin_amdgcn_mfma_f32_16x16x32_f16(ah, bh, acc[t][cb], 0, 0, 0);
      }
    __syncthreads();
  }
  int row0 = bm + wave * 16 + fq * 4;
#pragma unroll
  for (int t = 0; t < 2; ++t) {
    int headi = blockIdx.x * 2 + t;
    int cbase = bn + t * 64;
    float asv[4], adv[4];
#pragma unroll
    for (int cb = 0; cb < 4; ++cb) {
      int col = cbase + cb * 16 + fm;
      asv[cb] = att_s[col];
      adv[cb] = att_d[col];
    }
#pragma unroll
    for (int r = 0; r < 4; ++r) {
      int row = row0 + r;
      float sp = 0.f, dp = 0.f;
#pragma unroll
      for (int cb = 0; cb < 4; ++cb) {
        float v = acc[t][cb][r];
        sp = fmaf(v, asv[cb], sp);
        dp = fmaf(v, adv[cb], dp);
        if (row < M) C[(long)row * 256 + cbase + cb * 16 + fm] = (_Float16)v;
      }
#pragma unroll
      for (int o = 1; o < 16; o <<= 1) {
        sp += __shfl_xor(sp, o);
        dp += __shfl_xor(dp, o);
      }
      if (fm == 0 && row < M) {
        a_s[(long)row * 4 + headi] = sp;
        a_d[(long)row * 4 + headi] = dp;
      }
    }
  }
}

// ---------------- fused fp16 MFMA head (r21) ----------------
__launch_bounds__(256)
__global__ void head_mfma_kernel(const _Float16* __restrict__ A, const _Float16* __restrict__ B,
                                 const float* __restrict__ lb1, const float* __restrict__ lw2,
                                 const float* __restrict__ lb2, float* __restrict__ out, int M) {
  __shared__ _Float16 As[64][40];
  __shared__ _Float16 Bs[64][40];
  int tid = threadIdx.x;
  int bm = blockIdx.x * 64;
  int lane = tid & 63, wave = tid >> 6;
  int srow = tid >> 2, sch = (tid & 3) * 8;
  const _Float16* Ap = A + (long)(bm + srow) * 256 + sch;
  const _Float16* Bp = B + (long)srow * 256 + sch;
  int fm = lane & 15, fq = lane >> 4;
  f32x4 acc[4];
#pragma unroll
  for (int cb = 0; cb < 4; ++cb) acc[cb] = (f32x4){0.f, 0.f, 0.f, 0.f};
  for (int k0 = 0; k0 < 256; k0 += 32) {
    uint4 va = *(const uint4*)(Ap + k0);
    uint4 vb = *(const uint4*)(Bp + k0);
    *(uint4*)&As[srow][sch] = va;
    *(uint4*)&Bs[srow][sch] = vb;
    __syncthreads();
    half8v ah = *(const half8v*)&As[wave * 16 + fm][fq * 8];
#pragma unroll
    for (int cb = 0; cb < 4; ++cb) {
      half8v bh = *(const half8v*)&Bs[cb * 16 + fm][fq * 8];
      acc[cb] = __builtin_amdgcn_mfma_f32_16x16x32_f16(ah, bh, acc[cb], 0, 0, 0);
    }
    __syncthreads();
  }
  float lb1c[4], w20[4], w21[4];
#pragma unroll
  for (int cb = 0; cb < 4; ++cb) {
    int col = cb * 16 + fm;
    lb1c[cb] = lb1[col];
    w20[cb] = lw2[col * 2 + 0];
    w21[cb] = lw2[col * 2 + 1];
  }
  float b20 = lb2[0], b21 = lb2[1];
#pragma unroll
  for (int r = 0; r < 4; ++r) {
    float v0 = 0.f, v1 = 0.f;
#pragma unroll
    for (int cb = 0; cb < 4; ++cb) {
      float s = fmaxf(acc[cb][r] + lb1c[cb], 0.f);
      v0 = fmaf(s, w20[cb], v0);
      v1 = fmaf(s, w21[cb], v1);
    }
#pragma unroll
    for (int o = 1; o < 16; o <<= 1) {
      v0 += __shfl_xor(v0, o);
      v1 += __shfl_xor(v1, o);
    }
    if (fm == 0) {
      int row = bm + wave * 16 + fq * 4 + r;
      if (row < M) {
        v0 += b20;
        v1 += b21;
        float mx = fmaxf(v0, v1);
        float ls = mx + logf(expf(v0 - mx) + expf(v1 - mx));
        out[(long)row * 2 + 0] = v0 - ls;
        out[(long)row * 2 + 1] = v1 - ls;
      }
    }
  }
}

// ---------------- 2-half XCD-pinned aggregation, 1 node/wave ---------------
// bid&7 -> XCD (round-robin); half = (bid&7)>>2 (cols half*128..+127, heads
// hb0=half*2, hb0+1). grp = (bid>>3)*4 + (bid&3); wid = grp*4 + wave.
// lane roles: c16 = lane&15 (8-col group), quarter = lane>>4 (4 edges in
// flight); logit roles: le = lane>>2 (16 edges), lh = lane&1 (head in half).
// alpha = exp(lrelu(l)) (no-max, r24/25-verified). Each half computes its
// heads' full z independently; output cols disjoint -> row-major h works.
__launch_bounds__(256)
__global__ void gat_aggregate_half_kernel(const _Float16* __restrict__ h,
                                          const float* __restrict__ a_s,
                                          const float* __restrict__ a_d,
                                          const int* __restrict__ off,
                                          const int* __restrict__ csr_src,
                                          const float* __restrict__ bias,
                                          _Float16* __restrict__ outp, int N) {
  int bid = blockIdx.x;
  int xslot = bid & 7;
  int half = xslot >> 2;
  int grp = (bid >> 3) * 4 + (xslot & 3);
  int wave = threadIdx.x >> 6, lane = threadIdx.x & 63;
  int wid = grp * 4 + wave;
  if (wid >= N) return;
  int c16 = lane & 15, quarter = lane >> 4;
  int le = lane >> 2, lh = lane & 1;
  int hb0 = half * 2;
  int hh = c16 >> 3;                      // head-in-half for my columns
  int cbase = half * 128 + c16 * 8;       // my 8 columns
  int beg = off[wid], cnt = off[wid + 1] - beg;
  float ad_lh = a_d[(long)wid * 4 + hb0 + lh];
  // self term: lane l in {0,1} holds head hb0+l
  float pslf = __expf(lrelu(a_s[(long)wid * 4 + hb0 + lh] + ad_lh));
  float pself = __shfl(pslf, hh);
  float z = 0.f;
  float acc[8] = {};
  if (quarter == 0) {
    z = pself;
    half8v sr = *(const half8v*)(h + (long)wid * 256 + cbase);
#pragma unroll
    for (int i = 0; i < 8; ++i) acc[i] = pself * (float)sr[i];
  }
  for (int c0 = 0; c0 < cnt; c0 += 16) {
    int i2 = c0 + c16;
    int sv = (i2 < cnt) ? csr_src[beg + i2] : 0;
    int i1 = c0 + le;
    int spi = __shfl(sv, le);
    float pv = (i1 < cnt) ? __expf(lrelu(a_s[(long)spi * 4 + hb0 + lh] + ad_lh)) : 0.f;
#pragma unroll
    for (int j = 0; j < 4; ++j) {
      if (c0 + j * 4 >= cnt) break;
      int e = j * 4 + quarter;
      int s = __shfl(sv, e);
      float p = __shfl(pv, e * 4 + hh);   // pv lane e*4+{0,1} = heads {0,1}
      z += p;
      half8v rv = *(const half8v*)(h + (long)s * 256 + cbase);
      acc[0] = fmaf(p, (float)rv[0], acc[0]);
      acc[1] = fmaf(p, (float)rv[1], acc[1]);
      acc[2] = fmaf(p, (float)rv[2], acc[2]);
      acc[3] = fmaf(p, (float)rv[3], acc[3]);
      acc[4] = fmaf(p, (float)rv[4], acc[4]);
      acc[5] = fmaf(p, (float)rv[5], acc[5]);
      acc[6] = fmaf(p, (float)rv[6], acc[6]);
      acc[7] = fmaf(p, (float)rv[7], acc[7]);
    }
  }
  // reduce across the 4 quarters (lane bits 4,5)
  z += __shfl_xor(z, 16);
  z += __shfl_xor(z, 32);
#pragma unroll
  for (int i = 0; i < 8; ++i) {
    acc[i] += __shfl_xor(acc[i], 16);
    acc[i] += __shfl_xor(acc[i], 32);
  }
  if (quarter == 0) {
    float inv = 1.f / z;  // z >= pself > 0
    half8v o;
#pragma unroll
    for (int i = 0; i < 8; ++i) o[i] = (_Float16)elu1(fmaf(acc[i], inv, bias[cbase + i]));
    *(half8v*)(outp + (long)wid * 256 + cbase) = o;
  }
}

// ---------------------------------------------------------------------------
static inline int cdiv(int a, int b) { return (a + b - 1) / b; }

extern "C" void kernel_launch(void* const* d_in, const int* in_sizes, int n_in,
                              void* d_out, int out_size, void* d_ws, size_t ws_size,
                              hipStream_t stream) {
  const float* x = (const float*)d_in[0];
  const int* ei = (const int*)d_in[1];
  const float* W1 = (const float*)d_in[2];
  const float* as1 = (const float*)d_in[3];
  const float* ad1 = (const float*)d_in[4];
  const float* b1 = (const float*)d_in[5];
  const float* W2 = (const float*)d_in[6];
  const float* as2 = (const float*)d_in[7];
  const float* ad2 = (const float*)d_in[8];
  const float* b2 = (const float*)d_in[9];
  const float* lw1 = (const float*)d_in[10];
  const float* lb1 = (const float*)d_in[11];
  const float* lw2 = (const float*)d_in[12];
  const float* lb2 = (const float*)d_in[13];
  float* out = (float*)d_out;

  int N = in_sizes[0] / 128;  // 50000
  int E = in_sizes[1] / 2;    // 800000
  int Mp = cdiv(N, 64) * 64;  // 50048

  char* ws = (char*)d_ws;
  _Float16* Wt1 = (_Float16*)ws; ws += 256 * 128 * 2;
  _Float16* Wt2 = (_Float16*)ws; ws += 256 * 256 * 2;
  _Float16* WL = (_Float16*)ws; ws += 64 * 256 * 2;
  _Float16* C = (_Float16*)ws; ws += (size_t)Mp * 256 * 2;   // GEMM out
  _Float16* h2 = (_Float16*)ws; ws += (size_t)Mp * 256 * 2;  // aggregate out
  float* aS = (float*)ws; ws += (size_t)N * 4 * 4;
  float* aD = (float*)ws; ws += (size_t)N * 4 * 4;
  int* csr_src = (int*)ws; ws += (size_t)E * 4;
  int* indeg = (int*)ws; ws += (size_t)N * 4;
  int* cursor = (int*)ws; ws += (size_t)N * 4;
  int* off = (int*)ws; ws += (size_t)(N + 4) * 4;
  int* incl = (int*)ws; ws += (size_t)N * 4;
  int* bsum = (int*)ws; ws += 64 * 4;

  const int* e_src = ei;
  const int* e_dst = ei + E;
  int nb = cdiv(N, 1024);

  // weight conversion + indeg zeroing (one launch)
  convert_weights_kernel<<<cdiv(114688 + N, 256), 256, 0, stream>>>(W1, W2, lw1, Wt1, Wt2, WL,
                                                                    indeg, N);

  // CSR build
  count_kernel<<<cdiv(E, 256), 256, 0, stream>>>(e_dst, E, indeg);
  scan_block_kernel<<<nb, 1024, 0, stream>>>(indeg, incl, bsum, N);
  scan_finalize_kernel<<<cdiv(N, 256), 256, 0, stream>>>(indeg, incl, bsum, off, cursor, N);
  fill_kernel<<<cdiv(E, 256), 256, 0, stream>>>(e_src, e_dst, E, cursor, csr_src);

  // aggregate grid: 8 xcd-slots x node-groups (4 nodes per wave-group of 4)
  int agg_blocks = 8 * cdiv(cdiv(N, 4), 4);

  // Layer 1 (K=128, fp32 A converted in staging)
  mfma_gemm_attn_kernel<float><<<dim3(2, Mp / 64), 256, 0, stream>>>(x, Wt1, as1, ad1, C, aS, aD,
                                                                     N, 128);
  gat_aggregate_half_kernel<<<agg_blocks, 256, 0, stream>>>(C, aS, aD, off, csr_src, b1, h2, N);

  // Layer 2 (K=256, fp16 A)
  mfma_gemm_attn_kernel<_Float16><<<dim3(2, Mp / 64), 256, 0, stream>>>(h2, Wt2, as2, ad2, C, aS,
                                                                        aD, N, 256);
  gat_aggregate_half_kernel<<<agg_blocks, 256, 0, stream>>>(C, aS, aD, off, csr_src, b2, h2, N);

  // Head (MFMA, fused epilogue)
  head_mfma_kernel<<<Mp / 64, 256, 0, stream>>>(h2, WL, lb1, lw2, lb2, out, N);
}